// Round 13
// baseline (157.081 us; speedup 1.0000x reference)
//
#include <hip/hip_runtime.h>
#include <hip/hip_bf16.h>

#define T_DIM 8192
#define H_DIM 2048
#define D_DIM 1024
#define KT    16          // K tiles of BK=64
#define USTR  164         // u-tile col stride (u16), mult of 4 for b64 align

typedef __bf16 bf16x8 __attribute__((ext_vector_type(8)));
typedef float floatx4 __attribute__((ext_vector_type(4)));
typedef unsigned short u16;
typedef unsigned short u16x8 __attribute__((ext_vector_type(8)));

__device__ __forceinline__ u16 f2bf(float f) {
    __hip_bfloat16 b = __float2bfloat16(f);
    return *reinterpret_cast<u16*>(&b);
}
__device__ __forceinline__ float bf2f(u16 v) {
    return __uint_as_float((unsigned)v << 16);
}

#define GLDS(g, l) \
    __builtin_amdgcn_global_load_lds((const __attribute__((address_space(1))) void*)(g), \
                                     (__attribute__((address_space(3))) void*)(l), 16, 0, 0)

// ---------------------------------------------------------------------------
// fp32 -> bf16 convert for B ONLY (x is now consumed directly by the gemm's
// reg-staged A path). 12MB traffic -> ~2us.
// ---------------------------------------------------------------------------
__global__ __launch_bounds__(256) void conv_kernel(const float* __restrict__ Bm,
                                                   u16* __restrict__ bb) {
    const int nB4 = H_DIM * D_DIM / 4;
    int i = blockIdx.x * 256 + threadIdx.x;
    if (i >= nB4) return;
    const float4 v = reinterpret_cast<const float4*>(Bm)[i];
    ushort4 o;
    o.x = f2bf(v.x); o.y = f2bf(v.y); o.z = f2bf(v.z); o.w = f2bf(v.w);
    reinterpret_cast<ushort4*>(bb)[i] = o;
}

// ---------------------------------------------------------------------------
// Fused 160x128 GEMM + scan, r7 skeleton (2-phase/K-tile, 2 blocks/CU, best
// measured plateau class) with A consumed DIRECTLY FROM x (fp32): reg-stage
// global float4 x2 per unit -> cvt (RTN, identical to old conv) -> one
// ds_write_b128. Removes the 8us x-materialization round-trip. Warm-up pad
// becomes a bm==0 register-zero guard (unit 0 = rows -32..0 -> zeros).
// 256 thr = 4 waves (2M x 2N), per-wave 80x64 (acc[5][4]), BK=64, KT=16.
// LDS 73728B: A dbuf 2x[160][64] + B dbuf 2x[128][64] -> 2 blocks/CU.
// P1(t): ds_read af(10)+b0(4) | b1(4) pinned; issue A(t+1) fp32 loads (10
//   dwordx4; 8 if bm==0) -> regs; LGKM(4) -> MFMA b0 (20); LGKM(0) [b1
//   drained -> P2 B-restage overwrite-safe]; BAR.
// P2(t): GLDS B(t+2)x4 -> same-parity B-buf; MFMA b1 (20); vmcnt(4)
//   [ledger oldest->newest: B(t+1)x4, A(t+1)x{10|8}, B(t+2)x4 -> keep 4 =
//   B(t+2); A count drops out -> uniform both block classes]; WRITE_A(t+1)
//   (cvt+5 ds_write_b128 -> opposite A-buf, last read P1(t)); LGKM0; BAR.
// Tail: vmcnt(0) from t=KT-2; no A issue/write for t+1>=KT.
// x locality: T1 sweeps 16 bn-blocks per bm on one XCD -> A rows L2-warm
// (640KB << 4MB); HBM fetch ~unchanged. Bytes written to LDS are identical
// to the GLDS-from-xb version (same pre-swizzled granule cS, same dest).
// Granule-XOR swizzle (col ^= (row&7)*8) both sides -> 0 bank conflicts.
// Epilogue (r12 verbatim): u-tile col-major [128][USTR] bf16 (b64 repack),
// 2 half-scans per column (32 warm + 64 out), coalesced fp32 out.
// ---------------------------------------------------------------------------
__device__ __forceinline__ bf16x8 lds_frag(const u16* base, int row, int kx, int kseg) {
    const int cp = (kx + kseg * 8) ^ ((row & 7) * 8);
    return *reinterpret_cast<const bf16x8*>(base + row * 64 + cp);
}

#define MFMA_Q(NH, BF)                                                               \
    _Pragma("unroll")                                                                \
    for (int kx = 0; kx < 2; ++kx)                                                   \
        _Pragma("unroll")                                                            \
        for (int mi = 0; mi < 5; ++mi)                                               \
            _Pragma("unroll")                                                        \
            for (int nj = 0; nj < 2; ++nj)                                           \
                acc[mi][(NH) * 2 + nj] = __builtin_amdgcn_mfma_f32_16x16x32_bf16(    \
                    af[mi][kx], BF[nj][kx], acc[mi][(NH) * 2 + nj], 0, 0, 0);

#define STAGE_B(GB2, DB)                                                             \
    _Pragma("unroll")                                                                \
    for (int u = 0; u < 4; ++u)                                                      \
        GLDS((GB2) + (size_t)(u * 32) * D_DIM, (DB) + u * 2048 + tid * 8);

// issue A-tile T's fp32 loads into av (bm==0: unit 0 = warm rows -> zeros)
#define LOAD_A(T)                                                                    \
    _Pragma("unroll")                                                                \
    for (int u = 0; u < 5; ++u) {                                                    \
        if (u == 0 && bm == 0) {                                                     \
            av[0] = make_float4(0.f, 0.f, 0.f, 0.f);                                 \
            av[1] = make_float4(0.f, 0.f, 0.f, 0.f);                                 \
        } else {                                                                     \
            const float* p = gx + (size_t)(u * 32) * D_DIM + (T) * 64;               \
            av[u * 2]     = *reinterpret_cast<const float4*>(p);                     \
            av[u * 2 + 1] = *reinterpret_cast<const float4*>(p + 4);                 \
        }                                                                            \
    }

// cvt av -> bf16, ds_write_b128 x5 into A-buf of tile T (same bytes/dest as
// the old global_load_lds-from-xb path)
#define WRITE_A(T)                                                                   \
    {                                                                                \
        u16* dA = sA + (((T) & 1) ? 10240 : 0);                                      \
        _Pragma("unroll")                                                            \
        for (int u = 0; u < 5; ++u) {                                                \
            u16x8 w;                                                                 \
            w[0] = f2bf(av[u * 2].x);     w[1] = f2bf(av[u * 2].y);                  \
            w[2] = f2bf(av[u * 2].z);     w[3] = f2bf(av[u * 2].w);                  \
            w[4] = f2bf(av[u * 2 + 1].x); w[5] = f2bf(av[u * 2 + 1].y);              \
            w[6] = f2bf(av[u * 2 + 1].z); w[7] = f2bf(av[u * 2 + 1].w);              \
            *reinterpret_cast<u16x8*>(dA + u * 2048 + tid * 8) = w;                  \
        }                                                                            \
    }

#define PH_BAR()    __builtin_amdgcn_s_barrier()
#define SCHEDB()    __builtin_amdgcn_sched_barrier(0)
#define LGKM(N)     do { asm volatile("s_waitcnt lgkmcnt(" #N ")" ::: "memory"); \
                         SCHEDB(); } while (0)

__global__ __launch_bounds__(256, 2) void gemm_kernel(const float* __restrict__ x,
                                                      const u16* __restrict__ bb,
                                                      const float* __restrict__ lam,
                                                      float* __restrict__ out) {
    __shared__ alignas(16) u16 smem[36864];   // 73728 B -> 2 blocks/CU
    u16* sA = smem;                    // 2 bufs x 10240 u16 ([160][64])
    u16* sB = smem + 20480;            // 2 bufs x  8192 u16 ([128][64])

    const int tid  = threadIdx.x;
    const int lane = tid & 63;
    const int wid  = tid >> 6;         // 0..3
    const int lrow = lane & 15;
    const int kseg = lane >> 4;
    const int wm   = (wid >> 1) * 80;
    const int wn   = (wid & 1) * 64;

    // T1: XCD-aware mapping (bijective; 1024 blocks = 8 xcd x 16 bn x 8 bm).
    const int bid = blockIdx.x;
    const int xcd = bid & 7, idx = bid >> 3;
    const int bn  = idx & 15;                  // 0..15
    const int bm  = xcd * 8 + (idx >> 4);      // 0..63

    // staging map: 32 rows per unit, 8 thr/row; granule-permuted col cS so
    // linear LDS dest + swizzled reader stay consistent (both A and B).
    const int rS = tid >> 3;                   // 0..31
    const int cS = ((tid & 7) * 8) ^ ((rS & 7) * 8);
    // A source: fp32 x, rows shifted -32 (warm-up window; bm==0 guarded)
    const float* gx = x + (size_t)(bm * 128 + rS - 32) * D_DIM + cS;
    const u16*   gB = bb + (size_t)(bn * 128 + rS) * D_DIM + cS;

    floatx4 acc[5][4] = {};
    bf16x8 af[5][2], b0[2][2], b1[2][2];
    float4 av[10];

    // ---- prologue: issue A(0) loads; GLDS B(0),B(1); vmcnt(4) retires
    // A(0)+B(0) (A count 10 or 8 -- drops out), keeps B(1); write A(0).
    LOAD_A(0)
    STAGE_B(gB, sB)
    STAGE_B(gB + 64, sB + 8192)
    asm volatile("s_waitcnt vmcnt(4)" ::: "memory");
    WRITE_A(0)
    LGKM(0);
    PH_BAR();

#pragma unroll 2
    for (int t = 0; t < KT; ++t) {
        const u16* cA = sA + (t & 1) * 10240;
        const u16* cB = sB + (t & 1) * 8192;
        u16* dB       = sB + (t & 1) * 8192;          // B(t+2): same parity

        // ======== P1: ds_read af(10)+b0(4) | b1(4); issue A(t+1) loads
#pragma unroll
        for (int mi = 0; mi < 5; ++mi)
#pragma unroll
            for (int kx = 0; kx < 2; ++kx)
                af[mi][kx] = lds_frag(cA, wm + mi * 16 + lrow, kx * 32, kseg);
#pragma unroll
        for (int nj = 0; nj < 2; ++nj)
#pragma unroll
            for (int kx = 0; kx < 2; ++kx)
                b0[nj][kx] = lds_frag(cB, wn + nj * 16 + lrow, kx * 32, kseg);
        SCHEDB();   // pin: b1 reads issue AFTER the 14 above (counted lgkm)
#pragma unroll
        for (int nj = 0; nj < 2; ++nj)
#pragma unroll
            for (int kx = 0; kx < 2; ++kx)
                b1[nj][kx] = lds_frag(cB, wn + 32 + nj * 16 + lrow, kx * 32, kseg);
        SCHEDB();
        if (t + 1 < KT) {
            LOAD_A(t + 1)
        }
        LGKM(4);                       // af + b0 landed (DS returns in-order)
        MFMA_Q(0, b0)
        LGKM(0);                       // b1 landed -> P2 B-restage is safe
        PH_BAR();

        // ======== P2: stage B(t+2); MFMA b1; counted vmcnt; write A(t+1)
        if (t + 2 < KT) {
            STAGE_B(gB + (size_t)(t + 2) * 64, dB)
        }
        MFMA_Q(1, b1)
        if (t < KT - 2) asm volatile("s_waitcnt vmcnt(4)" ::: "memory");
        else            asm volatile("s_waitcnt vmcnt(0)" ::: "memory");
        if (t + 1 < KT) {
            WRITE_A(t + 1)
        }
        LGKM(0);                       // A-writes visible before barrier
        PH_BAR();
    }

    // ---- epilogue 1: acc -> LDS u-tile, COLUMN-major [128][USTR] bf16.
    // Lane's 4 acc values (rows r0..r0+3 of one col) -> one ds_write_b64.
    u16* ut = smem;
#pragma unroll
    for (int mi = 0; mi < 5; ++mi)
#pragma unroll
        for (int nj = 0; nj < 4; ++nj) {
            const int col  = wn + nj * 16 + lrow;
            const int row0 = wm + mi * 16 + kseg * 4;
            ushort4 w;
            w.x = f2bf(acc[mi][nj][0]); w.y = f2bf(acc[mi][nj][1]);
            w.z = f2bf(acc[mi][nj][2]); w.w = f2bf(acc[mi][nj][3]);
            *reinterpret_cast<ushort4*>(ut + col * USTR + row0) = w;
        }
    __syncthreads();

    // ---- epilogue 2: two parallel half-scans per column (32 warm + 64 out),
    // ds_read_b64 (4 rows per read), coalesced fp32 stores.
    {
        const int half = tid >> 7;          // 0 or 1
        const int c    = tid & 127;
        const float a  = 1.0f / (1.0f + __expf(-lam[bn * 128 + c]));
        const u16* colp = ut + c * USTR;
        const int rb = half * 64;
        float h = 0.0f;
#pragma unroll
        for (int qb = 0; qb < 8; ++qb) {
            const ushort4 v = *reinterpret_cast<const ushort4*>(colp + rb + qb * 4);
            h = fmaf(a, h, bf2f(v.x)); h = fmaf(a, h, bf2f(v.y));
            h = fmaf(a, h, bf2f(v.z)); h = fmaf(a, h, bf2f(v.w));
        }
        float* op = out + (size_t)(bm * 128 + rb) * H_DIM + bn * 128 + c;
#pragma unroll 8
        for (int qb = 0; qb < 16; ++qb) {
            const ushort4 v = *reinterpret_cast<const ushort4*>(colp + rb + 32 + qb * 4);
            h = fmaf(a, h, bf2f(v.x)); op[(size_t)(qb * 4 + 0) * H_DIM] = h;
            h = fmaf(a, h, bf2f(v.y)); op[(size_t)(qb * 4 + 1) * H_DIM] = h;
            h = fmaf(a, h, bf2f(v.z)); op[(size_t)(qb * 4 + 2) * H_DIM] = h;
            h = fmaf(a, h, bf2f(v.w)); op[(size_t)(qb * 4 + 3) * H_DIM] = h;
        }
    }
}

// ---------------------------------------------------------------------------
extern "C" void kernel_launch(void* const* d_in, const int* in_sizes, int n_in,
                              void* d_out, int out_size, void* d_ws, size_t ws_size,
                              hipStream_t stream) {
    const float* x   = (const float*)d_in[0];   // [T, D]
    const float* lam = (const float*)d_in[1];   // [H]
    const float* B   = (const float*)d_in[2];   // [H, D]
    float* out = (float*)d_out;                 // [T, H]

    // ws: bb [H][D] bf16 (4.2MB). x is consumed directly by gemm.
    u16* bb = (u16*)d_ws;

    const int nB4 = H_DIM * D_DIM / 4;
    conv_kernel<<<(nB4 + 255) / 256, 256, 0, stream>>>(B, bb);
    gemm_kernel<<<(H_DIM / 128) * (T_DIM / 128), 256, 0, stream>>>(x, bb, lam, out);
}